// Round 4
// baseline (88.474 us; speedup 1.0000x reference)
//
#include <hip/hip_runtime.h>
#include <hip/hip_cooperative_groups.h>
#include <stdint.h>
#include <string.h>

namespace cg = cooperative_groups;

// JAX >= 0.4.36 partitionable threefry. Validated bit-exact (absmax 0.0, r1-r3).
#define JAX_THREEFRY_PARTITIONABLE 1

#define DIN 100
#define DHID 512
#define DOUT 200
#define NPATH_AGG 5
#define NFINAL 10
#define MAXLEN 4
#define NSLOT (MAXLEN * NFINAL)   // 40 final (t, walk) slots
#define NE 16                     // dedup'd agg entries: [0]=start(x5), 1..15
#define QSPLIT 4                  // phase-1 blocks per slot (hidden-unit quarters)
#define NBLK_P1 (NSLOT * QSPLIT)  // 160
#define GRID_TOT DOUT             // 200 blocks total (>= NBLK_P1)

struct RngConsts {
  uint32_t kA[3][2];        // fold_in(fold_in(key(42),0), j), j=0..2
  int      starts2[NFINAL]; // jax.random.randint(fold_in(kw,1),(10,),0,N)
  float    u2[3][NFINAL];   // uniforms for the 10 final walks, steps 0..2
  int      N, maxd_bi, maxd_dir;
};

// ---------------- Threefry-2x32 (20 rounds), exactly as in jax._src.prng ---
__host__ __device__ inline void tf2x32(uint32_t k0, uint32_t k1,
                                       uint32_t& x0, uint32_t& x1) {
  const uint32_t k2 = k0 ^ k1 ^ 0x1BD11BDAu;
  x0 += k0; x1 += k1;
#define TFR(r) { x0 += x1; x1 = (x1 << (r)) | (x1 >> (32 - (r))); x1 ^= x0; }
  TFR(13) TFR(15) TFR(26) TFR(6)
  x0 += k1; x1 += k2 + 1u;
  TFR(17) TFR(29) TFR(16) TFR(24)
  x0 += k2; x1 += k0 + 2u;
  TFR(13) TFR(15) TFR(26) TFR(6)
  x0 += k0; x1 += k1 + 3u;
  TFR(17) TFR(29) TFR(16) TFR(24)
  x0 += k1; x1 += k2 + 4u;
  TFR(13) TFR(15) TFR(26) TFR(6)
  x0 += k2; x1 += k0 + 5u;
#undef TFR
}

__host__ __device__ inline uint32_t jax_bits32(uint32_t k0, uint32_t k1,
                                               uint32_t idx, uint32_t half) {
#if JAX_THREEFRY_PARTITIONABLE
  (void)half;
  uint32_t x0 = 0u, x1 = idx;   // 64-bit counter i -> (hi, lo) = (0, i)
  tf2x32(k0, k1, x0, x1);
  return x0 ^ x1;
#else
  uint32_t x0, x1;
  const bool lo = idx < half;
  if (lo) { x0 = idx;        x1 = idx + half; }
  else    { x0 = idx - half; x1 = idx;        }
  tf2x32(k0, k1, x0, x1);
  return lo ? x0 : x1;
#endif
}

__host__ __device__ inline float bits_to_unif(uint32_t bits) {
  uint32_t f = (bits >> 9) | 0x3F800000u;
  float r;
  memcpy(&r, &f, 4);
  return r - 1.0f;
}

// ---------------- Wave-parallel speculative walk step ----------------------
__device__ __forceinline__ void walk_step(const int* __restrict__ nbr,
                                          const int* __restrict__ deg,
                                          int maxd, int lane, float u,
                                          int& cur, int& valid) {
  const int d = deg[cur];
  const long long base = (long long)cur * maxd;
  int r0 = 0, r1 = 0, r2 = 0, r3 = 0;
  if (lane < maxd)       r0 = nbr[base + lane];
  if (lane + 64 < maxd)  r1 = nbr[base + lane + 64];
  if (lane + 128 < maxd) r2 = nbr[base + lane + 128];
  if (lane + 192 < maxd) r3 = nbr[base + lane + 192];
  int c = (int)(u * (float)d);
  const int cm = (d - 1 > 0) ? (d - 1) : 0;
  if (c > cm) c = cm;
  const int cl = c & 63;
  const int v0 = __shfl(r0, cl);
  const int v1 = __shfl(r1, cl);
  const int v2 = __shfl(r2, cl);
  const int v3 = __shfl(r3, cl);
  int v = (c < 64) ? v0 : (c < 128) ? v1 : (c < 192) ? v2 : v3;
  if (c >= 256) v = nbr[base + c];     // safety net (wave-uniform load)
  valid = valid && (d > 0);
  if (valid) cur = v;
}

// ---------------- Fused cooperative kernel ----------------------------------
// Phase 1 (blocks 0..159): block = (slot, quarter). Walks (redundant per
// quarter) + fc1 for 128 hidden units (4 lanes per unit, k-split).
// grid.sync()
// Phase 2 (blocks 0..199): block o computes out[o] = masked-mean of
// relu(agg[s].W3[o] + b3[o]).
__global__ __launch_bounds__(512) void k_fused(
    const float* __restrict__ x,
    const int* __restrict__ nbr_bi, const int* __restrict__ deg_bi,
    const int* __restrict__ nbr_dir, const int* __restrict__ deg_dir,
    const float* __restrict__ W1, const float* __restrict__ b1,
    const float* __restrict__ W3, const float* __restrict__ b3,
    RngConsts rc, int* __restrict__ maskArr, float* __restrict__ aggAll,
    float* __restrict__ out) {
  __shared__ int   vnode[NE];
  __shared__ int   vmask[NE];
  __shared__ float xs[NE][DIN];
  __shared__ int   maskS2[NSLOT];
  __shared__ float red[8];

  const int bid = blockIdx.x;
  const int tid = threadIdx.x;
  const int wv = tid >> 6, lane = tid & 63;

  if (bid < NBLK_P1) {
    const int slot = bid >> 2, q = bid & (QSPLIT - 1);
    const int w = slot % NFINAL, j = slot / NFINAL;

    // Final-walk prefix, recomputed redundantly by every wave (uniform).
    int cur = rc.starts2[w];
    int valid = 1;
    for (int t = 0; t < j; ++t)
      walk_step(nbr_dir, deg_dir, rc.maxd_dir, lane, rc.u2[t][w], cur, valid);

    if (q == 0 && tid == 0) maskArr[slot] = valid;

    if (valid) {
      const int n = cur;
      if (tid == 0) { vnode[0] = n; vmask[0] = 1; }
      // 5 agg walks; wave wv < 5 handles walk p = wv; walker id = p*N + n.
      if (wv < NPATH_AGG) {
        const uint32_t wkr = (uint32_t)(wv * rc.N + n);
        int c2 = n, v2 = 1;
#pragma unroll
        for (int jj = 0; jj < MAXLEN - 1; ++jj) {
          const float u = bits_to_unif(
              jax_bits32(rc.kA[jj][0], rc.kA[jj][1], wkr, 250000u));
          walk_step(nbr_bi, deg_bi, rc.maxd_bi, lane, u, c2, v2);
          if (lane == 0) {
            vnode[1 + jj * NPATH_AGG + wv] = c2;
            vmask[1 + jj * NPATH_AGG + wv] = v2;
          }
        }
      }
      __syncthreads();

      // Stage the 16 visited x rows into LDS (coalesced within rows).
      for (int idx = tid; idx < NE * DIN; idx += 512) {
        const int e = idx / DIN, k = idx % DIN;
        xs[e][k] = x[(long long)vnode[e] * DIN + k];
      }
      __syncthreads();

      // fc1: unit u = q*128 + (tid>>2); lane-split ks = tid&3 over k4.
      const int usub = tid >> 2, ks = tid & 3;
      const int unit = q * 128 + usub;
      const float4* __restrict__ w1r =
          (const float4*)(W1 + (long long)unit * DIN);
      float acc[NE];
#pragma unroll
      for (int e = 0; e < NE; ++e) acc[e] = 0.0f;
      for (int k4 = ks; k4 < DIN / 4; k4 += 4) {
        const float4 wv4 = w1r[k4];
        const float4* xrow = (const float4*)(&xs[0][0]);
#pragma unroll
        for (int e = 0; e < NE; ++e) {
          const float4 xv = *(const float4*)(&xs[e][k4 * 4]);
          acc[e] += wv4.x * xv.x + wv4.y * xv.y + wv4.z * xv.z + wv4.w * xv.w;
        }
        (void)xrow;
      }
      // Reduce each entry's partial over the 4 ks-lanes.
#pragma unroll
      for (int e = 0; e < NE; ++e) {
        float p = acc[e];
        p += __shfl_xor(p, 1);
        p += __shfl_xor(p, 2);
        acc[e] = p;
      }
      if (ks == 0) {
        float cntf = 5.0f;
#pragma unroll
        for (int e = 1; e < NE; ++e) cntf += (float)vmask[e];
        const float bb = b1[unit];
        float h0 = acc[0] + bb;
        h0 = (h0 > 0.0f) ? h0 : 0.0f;
        float hs = 5.0f * h0;
#pragma unroll
        for (int e = 1; e < NE; ++e) {
          if (vmask[e]) {
            const float hv = acc[e] + bb;
            hs += (hv > 0.0f) ? hv : 0.0f;
          }
        }
        aggAll[(long long)slot * DHID + unit] = hs / cntf;
      }
    }
  }

  __threadfence();
  cg::this_grid().sync();

  // ---- Phase 2: block o computes out[o] ----
  const int o = bid;
  if (o < DOUT) {
    if (tid < NSLOT) maskS2[tid] = maskArr[tid];
    __syncthreads();

    const float4* __restrict__ w4 = (const float4*)(W3 + (long long)o * DHID);
    const float4 g0 = w4[lane];
    const float4 g1 = w4[64 + lane];
    const float b3o = b3[o];

    float acc = 0.0f;
    for (int s = wv; s < NSLOT; s += 8) {
      if (maskS2[s]) {
        const float4* a4 = (const float4*)(aggAll + (long long)s * DHID);
        const float4 a0 = a4[lane];
        const float4 a1 = a4[64 + lane];
        float p = a0.x * g0.x + a0.y * g0.y + a0.z * g0.z + a0.w * g0.w
                + a1.x * g1.x + a1.y * g1.y + a1.z * g1.z + a1.w * g1.w;
#pragma unroll
        for (int off = 32; off; off >>= 1) p += __shfl_xor(p, off);
        const float r = p + b3o;
        acc += (r > 0.0f) ? r : 0.0f;
      }
    }
    if (lane == 0) red[wv] = acc;
    __syncthreads();
    if (tid == 0) {
      float wsum = 0.0f;
      for (int s = 0; s < NSLOT; ++s) wsum += (float)maskS2[s];
      float tot = 0.0f;
#pragma unroll
      for (int v = 0; v < 8; ++v) tot += red[v];
      out[o] = tot / wsum;
    }
  }
}

// ---------------- Host-side PRNG chain -------------------------------------
static void h_enc(const uint32_t k[2], uint32_t x0, uint32_t x1, uint32_t out[2]) {
  tf2x32(k[0], k[1], x0, x1);
  out[0] = x0; out[1] = x1;
}
static void h_foldin(const uint32_t k[2], uint32_t data, uint32_t out[2]) {
  h_enc(k, 0u, data, out);
}

extern "C" void kernel_launch(void* const* d_in, const int* in_sizes, int n_in,
                              void* d_out, int out_size, void* d_ws, size_t ws_size,
                              hipStream_t stream) {
  const float* x       = (const float*)d_in[0];
  const int*   nbr_bi  = (const int*)d_in[2];
  const int*   deg_bi  = (const int*)d_in[3];
  const int*   nbr_dir = (const int*)d_in[4];
  const int*   deg_dir = (const int*)d_in[5];
  const float* W1      = (const float*)d_in[6];
  const float* b1      = (const float*)d_in[7];
  const float* W3      = (const float*)d_in[8];
  const float* b3      = (const float*)d_in[9];

  const int N = in_sizes[0] / DIN;
  RngConsts rc;
  rc.N = N;
  rc.maxd_bi  = in_sizes[2] / N;
  rc.maxd_dir = in_sizes[4] / N;

  const uint32_t kw[2] = {0u, 42u};            // jax.random.key(42)
  uint32_t kA[2];
  h_foldin(kw, 0u, kA);
  for (uint32_t j = 0; j < 3; ++j) h_foldin(kA, j, rc.kA[j]);

  uint32_t kS[2];
  h_foldin(kw, 1u, kS);
  uint32_t k1_[2], k2_[2];
#if JAX_THREEFRY_PARTITIONABLE
  h_enc(kS, 0u, 0u, k1_);
  h_enc(kS, 0u, 1u, k2_);
#else
  {
    uint32_t a[2], b[2];
    h_enc(kS, 0u, 2u, a);
    h_enc(kS, 1u, 3u, b);
    k1_[0] = a[0]; k1_[1] = b[0];
    k2_[0] = a[1]; k2_[1] = b[1];
  }
#endif
  {
    const uint32_t span = (uint32_t)N;
    uint32_t mult = 65536u % span;
    mult = (uint32_t)(mult * mult) % span;     // uint32 wrap, like lax.mul
    for (uint32_t i = 0; i < NFINAL; ++i) {
      const uint32_t hi = jax_bits32(k1_[0], k1_[1], i, NFINAL / 2);
      const uint32_t lo = jax_bits32(k2_[0], k2_[1], i, NFINAL / 2);
      uint32_t off = (hi % span) * mult + (lo % span);
      off %= span;
      rc.starts2[i] = (int)off;
    }
  }

  uint32_t kP[2];
  h_foldin(kw, 2u, kP);
  for (uint32_t j = 0; j < 3; ++j) {
    uint32_t kPj[2];
    h_foldin(kP, j, kPj);
    for (uint32_t i = 0; i < NFINAL; ++i)
      rc.u2[j][i] = bits_to_unif(jax_bits32(kPj[0], kPj[1], i, NFINAL / 2));
  }

  // Workspace: maskArr[40] | aggAll[40*512] floats
  int*   maskArr = (int*)d_ws;
  float* aggAll  = (float*)(maskArr + NSLOT);
  float* outp    = (float*)d_out;

  void* args[] = {(void*)&x, (void*)&nbr_bi, (void*)&deg_bi, (void*)&nbr_dir,
                  (void*)&deg_dir, (void*)&W1, (void*)&b1, (void*)&W3,
                  (void*)&b3, (void*)&rc, (void*)&maskArr, (void*)&aggAll,
                  (void*)&outp};
  hipLaunchCooperativeKernel((const void*)k_fused, dim3(GRID_TOT), dim3(512),
                             args, 0, stream);
}

// Round 5
// 21.499 us; speedup vs baseline: 4.1153x; 4.1153x over previous
//
#include <hip/hip_runtime.h>
#include <stdint.h>
#include <string.h>

// JAX >= 0.4.36 partitionable threefry. Validated bit-exact (absmax 0.0, r1-r4).
#define JAX_THREEFRY_PARTITIONABLE 1

#define DIN 100
#define DHID 512
#define DOUT 200
#define NPATH_AGG 5
#define NFINAL 10
#define MAXLEN 4
#define NSLOT (MAXLEN * NFINAL)   // 40 final (t, walk) slots
#define NE 16                     // dedup'd agg entries: [0]=start(x5), 1..15
#define QSPLIT 4                  // blocks per slot (hidden-unit quarters)
#define NBLK_P1 (NSLOT * QSPLIT)  // 160

struct RngConsts {
  uint32_t kA[3][2];        // fold_in(fold_in(key(42),0), j), j=0..2
  int      starts2[NFINAL]; // jax.random.randint(fold_in(kw,1),(10,),0,N)
  float    u2[3][NFINAL];   // uniforms for the 10 final walks, steps 0..2
  int      N, maxd_bi, maxd_dir;
};

// ---------------- Threefry-2x32 (20 rounds), exactly as in jax._src.prng ---
__host__ __device__ inline void tf2x32(uint32_t k0, uint32_t k1,
                                       uint32_t& x0, uint32_t& x1) {
  const uint32_t k2 = k0 ^ k1 ^ 0x1BD11BDAu;
  x0 += k0; x1 += k1;
#define TFR(r) { x0 += x1; x1 = (x1 << (r)) | (x1 >> (32 - (r))); x1 ^= x0; }
  TFR(13) TFR(15) TFR(26) TFR(6)
  x0 += k1; x1 += k2 + 1u;
  TFR(17) TFR(29) TFR(16) TFR(24)
  x0 += k2; x1 += k0 + 2u;
  TFR(13) TFR(15) TFR(26) TFR(6)
  x0 += k0; x1 += k1 + 3u;
  TFR(17) TFR(29) TFR(16) TFR(24)
  x0 += k1; x1 += k2 + 4u;
  TFR(13) TFR(15) TFR(26) TFR(6)
  x0 += k2; x1 += k0 + 5u;
#undef TFR
}

__host__ __device__ inline uint32_t jax_bits32(uint32_t k0, uint32_t k1,
                                               uint32_t idx, uint32_t half) {
#if JAX_THREEFRY_PARTITIONABLE
  (void)half;
  uint32_t x0 = 0u, x1 = idx;   // 64-bit counter i -> (hi, lo) = (0, i)
  tf2x32(k0, k1, x0, x1);
  return x0 ^ x1;
#else
  uint32_t x0, x1;
  const bool lo = idx < half;
  if (lo) { x0 = idx;        x1 = idx + half; }
  else    { x0 = idx - half; x1 = idx;        }
  tf2x32(k0, k1, x0, x1);
  return lo ? x0 : x1;
#endif
}

__host__ __device__ inline float bits_to_unif(uint32_t bits) {
  uint32_t f = (bits >> 9) | 0x3F800000u;
  float r;
  memcpy(&r, &f, 4);
  return r - 1.0f;
}

// ---------------- Wave-parallel speculative walk step ----------------------
__device__ __forceinline__ void walk_step(const int* __restrict__ nbr,
                                          const int* __restrict__ deg,
                                          int maxd, int lane, float u,
                                          int& cur, int& valid) {
  const int d = deg[cur];
  const long long base = (long long)cur * maxd;
  int r0 = 0, r1 = 0, r2 = 0, r3 = 0;
  if (lane < maxd)       r0 = nbr[base + lane];
  if (lane + 64 < maxd)  r1 = nbr[base + lane + 64];
  if (lane + 128 < maxd) r2 = nbr[base + lane + 128];
  if (lane + 192 < maxd) r3 = nbr[base + lane + 192];
  int c = (int)(u * (float)d);
  const int cm = (d - 1 > 0) ? (d - 1) : 0;
  if (c > cm) c = cm;
  const int cl = c & 63;
  const int v0 = __shfl(r0, cl);
  const int v1 = __shfl(r1, cl);
  const int v2 = __shfl(r2, cl);
  const int v3 = __shfl(r3, cl);
  int v = (c < 64) ? v0 : (c < 128) ? v1 : (c < 192) ? v2 : v3;
  if (c >= 256) v = nbr[base + c];     // safety net (wave-uniform load)
  valid = valid && (d > 0);
  if (valid) cur = v;
}

// ---------------- Kernel A: (slot, quarter) -> walks + fc1 -----------------
// Block = (slot, q). Walks recomputed redundantly per quarter (parallel,
// same cache lines). fc1 computes 128 hidden units: 4 lanes per unit,
// k-split by tid&3, 2-step shfl reduce.
__global__ __launch_bounds__(512) void k_slot(
    const float* __restrict__ x,
    const int* __restrict__ nbr_bi, const int* __restrict__ deg_bi,
    const int* __restrict__ nbr_dir, const int* __restrict__ deg_dir,
    const float* __restrict__ W1, const float* __restrict__ b1,
    RngConsts rc, int* __restrict__ maskArr, float* __restrict__ aggAll) {
  __shared__ int   vnode[NE];
  __shared__ int   vmask[NE];
  __shared__ float xs[NE][DIN];

  const int bid = blockIdx.x;
  const int tid = threadIdx.x;
  const int wv = tid >> 6, lane = tid & 63;
  const int slot = bid >> 2, q = bid & (QSPLIT - 1);
  const int w = slot % NFINAL, j = slot / NFINAL;

  // Final-walk prefix, recomputed redundantly by every wave (uniform).
  int cur = rc.starts2[w];
  int valid = 1;
  for (int t = 0; t < j; ++t)
    walk_step(nbr_dir, deg_dir, rc.maxd_dir, lane, rc.u2[t][w], cur, valid);

  if (q == 0 && tid == 0) maskArr[slot] = valid;
  if (!valid) return;

  const int n = cur;
  if (tid == 0) { vnode[0] = n; vmask[0] = 1; }
  // 5 agg walks; wave wv < 5 handles walk p = wv; walker id = p*N + n.
  if (wv < NPATH_AGG) {
    const uint32_t wkr = (uint32_t)(wv * rc.N + n);
    int c2 = n, v2 = 1;
#pragma unroll
    for (int jj = 0; jj < MAXLEN - 1; ++jj) {
      const float u = bits_to_unif(
          jax_bits32(rc.kA[jj][0], rc.kA[jj][1], wkr, 250000u));
      walk_step(nbr_bi, deg_bi, rc.maxd_bi, lane, u, c2, v2);
      if (lane == 0) {
        vnode[1 + jj * NPATH_AGG + wv] = c2;
        vmask[1 + jj * NPATH_AGG + wv] = v2;
      }
    }
  }
  __syncthreads();

  // Stage the 16 visited x rows into LDS.
  for (int idx = tid; idx < NE * DIN; idx += 512) {
    const int e = idx / DIN, k = idx % DIN;
    xs[e][k] = x[(long long)vnode[e] * DIN + k];
  }
  __syncthreads();

  // fc1: unit = q*128 + (tid>>2); k-split ks = tid&3 over k4 blocks.
  const int usub = tid >> 2, ks = tid & 3;
  const int unit = q * 128 + usub;
  const float4* __restrict__ w1r = (const float4*)(W1 + (long long)unit * DIN);
  float acc[NE];
#pragma unroll
  for (int e = 0; e < NE; ++e) acc[e] = 0.0f;
  for (int k4 = ks; k4 < DIN / 4; k4 += 4) {
    const float4 wv4 = w1r[k4];
#pragma unroll
    for (int e = 0; e < NE; ++e) {
      const float4 xv = *(const float4*)(&xs[e][k4 * 4]);
      acc[e] += wv4.x * xv.x + wv4.y * xv.y + wv4.z * xv.z + wv4.w * xv.w;
    }
  }
#pragma unroll
  for (int e = 0; e < NE; ++e) {
    float p = acc[e];
    p += __shfl_xor(p, 1);
    p += __shfl_xor(p, 2);
    acc[e] = p;
  }
  if (ks == 0) {
    float cntf = 5.0f;
#pragma unroll
    for (int e = 1; e < NE; ++e) cntf += (float)vmask[e];
    const float bb = b1[unit];
    float h0 = acc[0] + bb;
    h0 = (h0 > 0.0f) ? h0 : 0.0f;
    float hs = 5.0f * h0;
#pragma unroll
    for (int e = 1; e < NE; ++e) {
      if (vmask[e]) {
        const float hv = acc[e] + bb;
        hs += (hv > 0.0f) ? hv : 0.0f;
      }
    }
    aggAll[(long long)slot * DHID + unit] = hs / cntf;
  }
}

// ---------------- Kernel B: per-output fc3 + fused masked mean -------------
__global__ __launch_bounds__(256) void k_fc3(
    const float* __restrict__ W3, const float* __restrict__ b3,
    const int* __restrict__ maskArr, const float* __restrict__ aggAll,
    float* __restrict__ out) {
  __shared__ int   maskS[NSLOT];
  __shared__ float partial[4];

  const int o = blockIdx.x;
  const int tid = threadIdx.x;
  const int wv = tid >> 6, lane = tid & 63;

  if (tid < NSLOT) maskS[tid] = maskArr[tid];
  __syncthreads();

  const float4* __restrict__ w4 = (const float4*)(W3 + (long long)o * DHID);
  const float4 g0 = w4[lane];
  const float4 g1 = w4[64 + lane];
  const float b3o = b3[o];

  float acc = 0.0f;
  for (int s = wv; s < NSLOT; s += 4) {
    if (maskS[s]) {
      const float4* a4 = (const float4*)(aggAll + (long long)s * DHID);
      const float4 a0 = a4[lane];
      const float4 a1 = a4[64 + lane];
      float p = a0.x * g0.x + a0.y * g0.y + a0.z * g0.z + a0.w * g0.w
              + a1.x * g1.x + a1.y * g1.y + a1.z * g1.z + a1.w * g1.w;
#pragma unroll
      for (int off = 32; off; off >>= 1) p += __shfl_xor(p, off);
      const float r = p + b3o;
      acc += (r > 0.0f) ? r : 0.0f;
    }
  }
  if (lane == 0) partial[wv] = acc;
  __syncthreads();
  if (tid == 0) {
    float wsum = 0.0f;
    for (int s = 0; s < NSLOT; ++s) wsum += (float)maskS[s];
    out[o] = (partial[0] + partial[1] + partial[2] + partial[3]) / wsum;
  }
}

// ---------------- Host-side PRNG chain -------------------------------------
static void h_enc(const uint32_t k[2], uint32_t x0, uint32_t x1, uint32_t out[2]) {
  tf2x32(k[0], k[1], x0, x1);
  out[0] = x0; out[1] = x1;
}
static void h_foldin(const uint32_t k[2], uint32_t data, uint32_t out[2]) {
  h_enc(k, 0u, data, out);
}

extern "C" void kernel_launch(void* const* d_in, const int* in_sizes, int n_in,
                              void* d_out, int out_size, void* d_ws, size_t ws_size,
                              hipStream_t stream) {
  const float* x       = (const float*)d_in[0];
  const int*   nbr_bi  = (const int*)d_in[2];
  const int*   deg_bi  = (const int*)d_in[3];
  const int*   nbr_dir = (const int*)d_in[4];
  const int*   deg_dir = (const int*)d_in[5];
  const float* W1      = (const float*)d_in[6];
  const float* b1      = (const float*)d_in[7];
  const float* W3      = (const float*)d_in[8];
  const float* b3      = (const float*)d_in[9];

  const int N = in_sizes[0] / DIN;
  RngConsts rc;
  rc.N = N;
  rc.maxd_bi  = in_sizes[2] / N;
  rc.maxd_dir = in_sizes[4] / N;

  const uint32_t kw[2] = {0u, 42u};            // jax.random.key(42)
  uint32_t kA[2];
  h_foldin(kw, 0u, kA);
  for (uint32_t j = 0; j < 3; ++j) h_foldin(kA, j, rc.kA[j]);

  uint32_t kS[2];
  h_foldin(kw, 1u, kS);
  uint32_t k1_[2], k2_[2];
#if JAX_THREEFRY_PARTITIONABLE
  h_enc(kS, 0u, 0u, k1_);
  h_enc(kS, 0u, 1u, k2_);
#else
  {
    uint32_t a[2], b[2];
    h_enc(kS, 0u, 2u, a);
    h_enc(kS, 1u, 3u, b);
    k1_[0] = a[0]; k1_[1] = b[0];
    k2_[0] = a[1]; k2_[1] = b[1];
  }
#endif
  {
    const uint32_t span = (uint32_t)N;
    uint32_t mult = 65536u % span;
    mult = (uint32_t)(mult * mult) % span;     // uint32 wrap, like lax.mul
    for (uint32_t i = 0; i < NFINAL; ++i) {
      const uint32_t hi = jax_bits32(k1_[0], k1_[1], i, NFINAL / 2);
      const uint32_t lo = jax_bits32(k2_[0], k2_[1], i, NFINAL / 2);
      uint32_t off = (hi % span) * mult + (lo % span);
      off %= span;
      rc.starts2[i] = (int)off;
    }
  }

  uint32_t kP[2];
  h_foldin(kw, 2u, kP);
  for (uint32_t j = 0; j < 3; ++j) {
    uint32_t kPj[2];
    h_foldin(kP, j, kPj);
    for (uint32_t i = 0; i < NFINAL; ++i)
      rc.u2[j][i] = bits_to_unif(jax_bits32(kPj[0], kPj[1], i, NFINAL / 2));
  }

  // Workspace: maskArr[40] | aggAll[40*512] floats
  int*   maskArr = (int*)d_ws;
  float* aggAll  = (float*)(maskArr + NSLOT);

  k_slot<<<NBLK_P1, 512, 0, stream>>>(x, nbr_bi, deg_bi, nbr_dir, deg_dir,
                                      W1, b1, rc, maskArr, aggAll);
  k_fc3<<<DOUT, 256, 0, stream>>>(W3, b3, maskArr, aggAll, (float*)d_out);
}

// Round 6
// 19.734 us; speedup vs baseline: 4.4833x; 1.0894x over previous
//
#include <hip/hip_runtime.h>
#include <stdint.h>
#include <string.h>

// JAX >= 0.4.36 partitionable threefry. Validated bit-exact (absmax 0.0, r1-r5).
#define JAX_THREEFRY_PARTITIONABLE 1

#define DIN 100
#define DHID 512
#define DOUT 200
#define NPATH_AGG 5
#define NFINAL 10
#define MAXLEN 4
#define NSLOT (MAXLEN * NFINAL)   // 40 final (t, walk) slots
#define NE 16                     // dedup'd agg entries: [0]=start(x5), 1..15
#define QSPLIT 8                  // blocks per slot (hidden-unit eighths)
#define NBLK_P1 (NSLOT * QSPLIT)  // 320 >= 256 CUs

struct RngConsts {
  uint32_t kA[3][2];        // fold_in(fold_in(key(42),0), j), j=0..2
  int      starts2[NFINAL]; // jax.random.randint(fold_in(kw,1),(10,),0,N)
  float    u2[3][NFINAL];   // uniforms for the 10 final walks, steps 0..2
  int      N, maxd_bi, maxd_dir;
};

// ---------------- Threefry-2x32 (20 rounds), exactly as in jax._src.prng ---
__host__ __device__ inline void tf2x32(uint32_t k0, uint32_t k1,
                                       uint32_t& x0, uint32_t& x1) {
  const uint32_t k2 = k0 ^ k1 ^ 0x1BD11BDAu;
  x0 += k0; x1 += k1;
#define TFR(r) { x0 += x1; x1 = (x1 << (r)) | (x1 >> (32 - (r))); x1 ^= x0; }
  TFR(13) TFR(15) TFR(26) TFR(6)
  x0 += k1; x1 += k2 + 1u;
  TFR(17) TFR(29) TFR(16) TFR(24)
  x0 += k2; x1 += k0 + 2u;
  TFR(13) TFR(15) TFR(26) TFR(6)
  x0 += k0; x1 += k1 + 3u;
  TFR(17) TFR(29) TFR(16) TFR(24)
  x0 += k1; x1 += k2 + 4u;
  TFR(13) TFR(15) TFR(26) TFR(6)
  x0 += k2; x1 += k0 + 5u;
#undef TFR
}

__host__ __device__ inline uint32_t jax_bits32(uint32_t k0, uint32_t k1,
                                               uint32_t idx, uint32_t half) {
#if JAX_THREEFRY_PARTITIONABLE
  (void)half;
  uint32_t x0 = 0u, x1 = idx;   // 64-bit counter i -> (hi, lo) = (0, i)
  tf2x32(k0, k1, x0, x1);
  return x0 ^ x1;
#else
  uint32_t x0, x1;
  const bool lo = idx < half;
  if (lo) { x0 = idx;        x1 = idx + half; }
  else    { x0 = idx - half; x1 = idx;        }
  tf2x32(k0, k1, x0, x1);
  return lo ? x0 : x1;
#endif
}

__host__ __device__ inline float bits_to_unif(uint32_t bits) {
  uint32_t f = (bits >> 9) | 0x3F800000u;
  float r;
  memcpy(&r, &f, 4);
  return r - 1.0f;
}

// ---------------- Wave-parallel speculative walk step ----------------------
__device__ __forceinline__ void walk_step(const int* __restrict__ nbr,
                                          const int* __restrict__ deg,
                                          int maxd, int lane, float u,
                                          int& cur, int& valid) {
  const int d = deg[cur];
  const long long base = (long long)cur * maxd;
  int r0 = 0, r1 = 0, r2 = 0, r3 = 0;
  if (lane < maxd)       r0 = nbr[base + lane];
  if (lane + 64 < maxd)  r1 = nbr[base + lane + 64];
  if (lane + 128 < maxd) r2 = nbr[base + lane + 128];
  if (lane + 192 < maxd) r3 = nbr[base + lane + 192];
  int c = (int)(u * (float)d);
  const int cm = (d - 1 > 0) ? (d - 1) : 0;
  if (c > cm) c = cm;
  const int cl = c & 63;
  const int v0 = __shfl(r0, cl);
  const int v1 = __shfl(r1, cl);
  const int v2 = __shfl(r2, cl);
  const int v3 = __shfl(r3, cl);
  int v = (c < 64) ? v0 : (c < 128) ? v1 : (c < 192) ? v2 : v3;
  if (c >= 256) v = nbr[base + c];     // safety net (wave-uniform load)
  valid = valid && (d > 0);
  if (valid) cur = v;
}

// Gather one x row (DIN floats) into LDS with 50 float2 lanes (overlappable).
__device__ __forceinline__ void stage_row(const float* __restrict__ x,
                                          float* __restrict__ dst,
                                          int node, int lane) {
  if (lane < DIN / 2) {
    *(float2*)(dst + lane * 2) =
        *(const float2*)(x + (long long)node * DIN + lane * 2);
  }
}

// ---------------- Kernel A: (slot, eighth) -> walks + fc1 ------------------
// Block = (slot, q), 512 threads. Walk-waves stage their visited x rows into
// LDS inline (row load overlaps next step's table round-trip). fc1 computes
// 64 hidden units: 8 lanes per unit, k-split by tid&7, 3-step shfl reduce.
__global__ __launch_bounds__(512) void k_slot(
    const float* __restrict__ x,
    const int* __restrict__ nbr_bi, const int* __restrict__ deg_bi,
    const int* __restrict__ nbr_dir, const int* __restrict__ deg_dir,
    const float* __restrict__ W1, const float* __restrict__ b1,
    RngConsts rc, int* __restrict__ maskArr, float* __restrict__ aggAll) {
  __shared__ int   vmask[NE];
  __shared__ float xs[NE][DIN];

  const int bid = blockIdx.x;
  const int tid = threadIdx.x;
  const int wv = tid >> 6, lane = tid & 63;
  const int slot = bid >> 3, q = bid & (QSPLIT - 1);
  const int w = slot % NFINAL, j = slot / NFINAL;

  // Final-walk prefix, recomputed redundantly by every wave (uniform,
  // same cache lines -> L1 hits after the first wave).
  int cur = rc.starts2[w];
  int valid = 1;
  for (int t = 0; t < j; ++t)
    walk_step(nbr_dir, deg_dir, rc.maxd_dir, lane, rc.u2[t][w], cur, valid);

  if (q == 0 && tid == 0) maskArr[slot] = valid;
  if (!valid) return;

  const int n = cur;
  if (tid == 0) vmask[0] = 1;

  if (wv < NPATH_AGG) {
    // Wave wv runs agg walk p = wv (walker id = p*N + n) and stages each
    // visited x row right after the step (load overlaps next step).
    const uint32_t wkr = (uint32_t)(wv * rc.N + n);
    int c2 = n, v2 = 1;
#pragma unroll
    for (int jj = 0; jj < MAXLEN - 1; ++jj) {
      const float u = bits_to_unif(
          jax_bits32(rc.kA[jj][0], rc.kA[jj][1], wkr, 250000u));
      walk_step(nbr_bi, deg_bi, rc.maxd_bi, lane, u, c2, v2);
      const int ent = 1 + jj * NPATH_AGG + wv;
      if (lane == 0) vmask[ent] = v2;
      stage_row(x, &xs[ent][0], c2, lane);
    }
  } else if (wv == 5) {
    stage_row(x, &xs[0][0], n, lane);  // start row, known immediately
  }
  __syncthreads();

  // fc1: unit = q*64 + (tid>>3); k-split ks = tid&7 over float4 blocks.
  const int usub = tid >> 3, ks = tid & 7;
  const int unit = q * 64 + usub;
  const float4* __restrict__ w1r = (const float4*)(W1 + (long long)unit * DIN);
  float acc[NE];
#pragma unroll
  for (int e = 0; e < NE; ++e) acc[e] = 0.0f;
  for (int k4 = ks; k4 < DIN / 4; k4 += 8) {
    const float4 wv4 = w1r[k4];
#pragma unroll
    for (int e = 0; e < NE; ++e) {
      const float4 xv = *(const float4*)(&xs[e][k4 * 4]);
      acc[e] += wv4.x * xv.x + wv4.y * xv.y + wv4.z * xv.z + wv4.w * xv.w;
    }
  }
#pragma unroll
  for (int e = 0; e < NE; ++e) {
    float p = acc[e];
    p += __shfl_xor(p, 1);
    p += __shfl_xor(p, 2);
    p += __shfl_xor(p, 4);
    acc[e] = p;
  }
  if (ks == 0) {
    float cntf = 5.0f;
#pragma unroll
    for (int e = 1; e < NE; ++e) cntf += (float)vmask[e];
    const float bb = b1[unit];
    float h0 = acc[0] + bb;
    h0 = (h0 > 0.0f) ? h0 : 0.0f;
    float hs = 5.0f * h0;
#pragma unroll
    for (int e = 1; e < NE; ++e) {
      if (vmask[e]) {
        const float hv = acc[e] + bb;
        hs += (hv > 0.0f) ? hv : 0.0f;
      }
    }
    aggAll[(long long)slot * DHID + unit] = hs / cntf;
  }
}

// ---------------- Kernel B: per-output fc3 + fused masked mean -------------
__global__ __launch_bounds__(512) void k_fc3(
    const float* __restrict__ W3, const float* __restrict__ b3,
    const int* __restrict__ maskArr, const float* __restrict__ aggAll,
    float* __restrict__ out) {
  __shared__ int   maskS[NSLOT];
  __shared__ float partial[8];

  const int o = blockIdx.x;
  const int tid = threadIdx.x;
  const int wv = tid >> 6, lane = tid & 63;

  if (tid < NSLOT) maskS[tid] = maskArr[tid];
  __syncthreads();

  const float4* __restrict__ w4 = (const float4*)(W3 + (long long)o * DHID);
  const float4 g0 = w4[lane];
  const float4 g1 = w4[64 + lane];
  const float b3o = b3[o];

  float acc = 0.0f;
#pragma unroll
  for (int i = 0; i < NSLOT / 8; ++i) {
    const int s = wv + i * 8;
    if (maskS[s]) {
      const float4* a4 = (const float4*)(aggAll + (long long)s * DHID);
      const float4 a0 = a4[lane];
      const float4 a1 = a4[64 + lane];
      float p = a0.x * g0.x + a0.y * g0.y + a0.z * g0.z + a0.w * g0.w
              + a1.x * g1.x + a1.y * g1.y + a1.z * g1.z + a1.w * g1.w;
#pragma unroll
      for (int off = 32; off; off >>= 1) p += __shfl_xor(p, off);
      const float r = p + b3o;
      acc += (r > 0.0f) ? r : 0.0f;
    }
  }
  if (lane == 0) partial[wv] = acc;
  __syncthreads();
  if (tid == 0) {
    float wsum = 0.0f;
    for (int s = 0; s < NSLOT; ++s) wsum += (float)maskS[s];
    float tot = 0.0f;
#pragma unroll
    for (int v = 0; v < 8; ++v) tot += partial[v];
    out[o] = tot / wsum;
  }
}

// ---------------- Host-side PRNG chain -------------------------------------
static void h_enc(const uint32_t k[2], uint32_t x0, uint32_t x1, uint32_t out[2]) {
  tf2x32(k[0], k[1], x0, x1);
  out[0] = x0; out[1] = x1;
}
static void h_foldin(const uint32_t k[2], uint32_t data, uint32_t out[2]) {
  h_enc(k, 0u, data, out);
}

extern "C" void kernel_launch(void* const* d_in, const int* in_sizes, int n_in,
                              void* d_out, int out_size, void* d_ws, size_t ws_size,
                              hipStream_t stream) {
  const float* x       = (const float*)d_in[0];
  const int*   nbr_bi  = (const int*)d_in[2];
  const int*   deg_bi  = (const int*)d_in[3];
  const int*   nbr_dir = (const int*)d_in[4];
  const int*   deg_dir = (const int*)d_in[5];
  const float* W1      = (const float*)d_in[6];
  const float* b1      = (const float*)d_in[7];
  const float* W3      = (const float*)d_in[8];
  const float* b3      = (const float*)d_in[9];

  const int N = in_sizes[0] / DIN;
  RngConsts rc;
  rc.N = N;
  rc.maxd_bi  = in_sizes[2] / N;
  rc.maxd_dir = in_sizes[4] / N;

  const uint32_t kw[2] = {0u, 42u};            // jax.random.key(42)
  uint32_t kA[2];
  h_foldin(kw, 0u, kA);
  for (uint32_t j = 0; j < 3; ++j) h_foldin(kA, j, rc.kA[j]);

  uint32_t kS[2];
  h_foldin(kw, 1u, kS);
  uint32_t k1_[2], k2_[2];
#if JAX_THREEFRY_PARTITIONABLE
  h_enc(kS, 0u, 0u, k1_);
  h_enc(kS, 0u, 1u, k2_);
#else
  {
    uint32_t a[2], b[2];
    h_enc(kS, 0u, 2u, a);
    h_enc(kS, 1u, 3u, b);
    k1_[0] = a[0]; k1_[1] = b[0];
    k2_[0] = a[1]; k2_[1] = b[1];
  }
#endif
  {
    const uint32_t span = (uint32_t)N;
    uint32_t mult = 65536u % span;
    mult = (uint32_t)(mult * mult) % span;     // uint32 wrap, like lax.mul
    for (uint32_t i = 0; i < NFINAL; ++i) {
      const uint32_t hi = jax_bits32(k1_[0], k1_[1], i, NFINAL / 2);
      const uint32_t lo = jax_bits32(k2_[0], k2_[1], i, NFINAL / 2);
      uint32_t off = (hi % span) * mult + (lo % span);
      off %= span;
      rc.starts2[i] = (int)off;
    }
  }

  uint32_t kP[2];
  h_foldin(kw, 2u, kP);
  for (uint32_t j = 0; j < 3; ++j) {
    uint32_t kPj[2];
    h_foldin(kP, j, kPj);
    for (uint32_t i = 0; i < NFINAL; ++i)
      rc.u2[j][i] = bits_to_unif(jax_bits32(kPj[0], kPj[1], i, NFINAL / 2));
  }

  // Workspace: maskArr[40] | aggAll[40*512] floats
  int*   maskArr = (int*)d_ws;
  float* aggAll  = (float*)(maskArr + NSLOT);

  k_slot<<<NBLK_P1, 512, 0, stream>>>(x, nbr_bi, deg_bi, nbr_dir, deg_dir,
                                      W1, b1, rc, maskArr, aggAll);
  k_fc3<<<DOUT, 512, 0, stream>>>(W3, b3, maskArr, aggAll, (float*)d_out);
}